// Round 1
// baseline (617.381 us; speedup 1.0000x reference)
//
#include <hip/hip_runtime.h>
#include <math.h>

// Problem constants
#define B_   64
#define T_   256
#define W_   20
#define NP_  6
#define NT_  12
#define CC_  32      // CONV_CH
#define FD_  8       // FRAG_DIM
#define PR_  64      // PROJ

__device__ __forceinline__ float sigmoidf_(float x) {
    return 1.0f / (1.0f + __expf(-x));
}
__device__ __forceinline__ float tanhf_(float x) {
    x = fminf(fmaxf(x, -15.0f), 15.0f);   // clamp so __expf never returns inf/inf
    float e = __expf(2.0f * x);
    return (e - 1.0f) / (e + 1.0f);
}

// -------------------------------------------------------------------------
// Kernel 1: per-window encoders + fragility + projection + LSTM input gates.
// One wave (64 threads) per (b,t) window; 16384 blocks.
// Lanes 0..31: pressure channel o=lane. Lanes 32..63: torque channel o=lane-32.
// Unified code path (divergent loop bound only) to avoid exec-mask serialization.
// -------------------------------------------------------------------------
__global__ __launch_bounds__(64) void encoder_kernel(
    const float* __restrict__ pressure, const float* __restrict__ torque,
    const float* __restrict__ frag,
    const float* __restrict__ pw1, const float* __restrict__ pb1,
    const float* __restrict__ pw2, const float* __restrict__ pb2,
    const float* __restrict__ tw1, const float* __restrict__ tb1,
    const float* __restrict__ tw2, const float* __restrict__ tb2,
    const float* __restrict__ fw,  const float* __restrict__ fb,
    const float* __restrict__ prw, const float* __restrict__ prb,
    const float* __restrict__ Wih, const float* __restrict__ bih,
    const float* __restrict__ bhh,
    float* __restrict__ xg)             // (B,T,256) output
{
    const int bt  = blockIdx.x;         // 0..16383
    const int b   = bt >> 8;            // T_=256
    const int tid = threadIdx.x;        // 0..63

    // LDS: window (transposed to [ch][w], rows padded to 20 = 80B, float4-aligned),
    // conv1 output rows padded to 20, concat vector, feature vector.
    __shared__ __align__(16) float xwin[360];    // [0..119]=pressure 6x20, [120..359]=torque 12x20
    __shared__ __align__(16) float h1[1280];     // [0..639]=h1p 32x20, [640..1279]=h1t 32x20
    __shared__ __align__(16) float catb[72];     // pf(32) | tf(32) | ff(8)
    __shared__ __align__(16) float featsh[64];

    // ---- stage window, transposing [w][i] -> [i][w] ----
    const float* pin = pressure + (size_t)bt * (W_ * NP_);
    for (int idx = tid; idx < W_ * NP_; idx += 64) {
        int w = idx / NP_, i = idx - w * NP_;
        xwin[i * 20 + w] = pin[idx];
    }
    const float* tin = torque + (size_t)bt * (W_ * NT_);
    for (int idx = tid; idx < W_ * NT_; idx += 64) {
        int w = idx / NT_, i = idx - w * NT_;
        xwin[120 + i * 20 + w] = tin[idx];
    }
    // fragility MLP -> catb[64..71]
    if (tid < FD_) catb[64 + tid] = fmaxf(frag[b] * fw[tid] + fb[tid], 0.0f);
    __syncthreads();

    // ---- conv1 (valid, K=3): in (nin,20) -> relu -> (32,18) ----
    {
        const int  o   = tid & 31;
        const bool isp = tid < 32;
        const float* xin = xwin + (isp ? 0 : 120);
        const float* w1  = isp ? (pw1 + o * (NP_ * 3)) : (tw1 + o * (NT_ * 3));
        const float  bz  = isp ? pb1[o] : tb1[o];
        const int    nin = isp ? NP_ : NT_;
        float acc[18];
        #pragma unroll
        for (int l = 0; l < 18; ++l) acc[l] = bz;
        for (int i = 0; i < nin; ++i) {
            float4 xr4[5];
            const float4* xrow = (const float4*)(xin + i * 20);
            #pragma unroll
            for (int q = 0; q < 5; ++q) xr4[q] = xrow[q];     // broadcast b128, no conflict
            const float* xr = (const float*)xr4;
            const float wk0 = w1[i * 3 + 0], wk1 = w1[i * 3 + 1], wk2 = w1[i * 3 + 2];
            #pragma unroll
            for (int l = 0; l < 18; ++l)
                acc[l] += xr[l] * wk0 + xr[l + 1] * wk1 + xr[l + 2] * wk2;
        }
        float* h1o = h1 + (isp ? 0 : 640) + o * 20;
        #pragma unroll
        for (int l = 0; l < 18; ++l) h1o[l] = fmaxf(acc[l], 0.0f);
    }
    __syncthreads();

    // ---- conv2 (32->32, K=3) + relu + mean over 16 positions ----
    {
        const int  o   = tid & 31;
        const bool isp = tid < 32;
        const float* h1i = h1 + (isp ? 0 : 640);
        const float* w2  = isp ? (pw2 + o * 96) : (tw2 + o * 96);
        const float  bz  = isp ? pb2[o] : tb2[o];
        float s[16];
        #pragma unroll
        for (int l = 0; l < 16; ++l) s[l] = bz;
        for (int i = 0; i < 32; ++i) {
            float4 hr4[5];
            const float4* hrow = (const float4*)(h1i + i * 20);
            #pragma unroll
            for (int q = 0; q < 5; ++q) hr4[q] = hrow[q];     // pad floats 18,19 unused
            const float* hr = (const float*)hr4;
            const float wk0 = w2[i * 3 + 0], wk1 = w2[i * 3 + 1], wk2 = w2[i * 3 + 2];
            #pragma unroll
            for (int l = 0; l < 16; ++l)
                s[l] += hr[l] * wk0 + hr[l + 1] * wk1 + hr[l + 2] * wk2;
        }
        float m = 0.0f;
        #pragma unroll
        for (int l = 0; l < 16; ++l) m += fmaxf(s[l], 0.0f);
        catb[tid] = m * 0.0625f;                 // pf -> catb[0..31], tf -> catb[32..63]
    }
    __syncthreads();

    // ---- projection 72 -> 64, relu ----
    {
        float acc = prb[tid];
        const float4* w4 = (const float4*)(prw + tid * 72);   // 288B row, 16B aligned
        const float4* c4 = (const float4*)catb;
        #pragma unroll
        for (int q = 0; q < 18; ++q) {
            float4 w = w4[q], cv = c4[q];
            acc += w.x * cv.x + w.y * cv.y + w.z * cv.z + w.w * cv.w;
        }
        featsh[tid] = fmaxf(acc, 0.0f);
    }
    __syncthreads();

    // ---- xg = feat @ Wih.T + bih + bhh : thread computes gates tid+64*{0..3} ----
    {
        float4 fr[16];
        const float4* f4 = (const float4*)featsh;
        #pragma unroll
        for (int q = 0; q < 16; ++q) fr[q] = f4[q];
        float* xgrow = xg + (size_t)bt * 256;
        #pragma unroll
        for (int gi = 0; gi < 4; ++gi) {
            const int g = tid + 64 * gi;
            const float4* w4 = (const float4*)(Wih + (size_t)g * 64);
            float acc = bih[g] + bhh[g];
            #pragma unroll
            for (int q = 0; q < 16; ++q) {
                float4 w = w4[q];
                acc += w.x * fr[q].x + w.y * fr[q].y + w.z * fr[q].z + w.w * fr[q].w;
            }
            xgrow[g] = acc;                      // coalesced per gi
        }
    }
}

// -------------------------------------------------------------------------
// Kernel 2: LSTM recurrence. One block per batch element (64 blocks x 256 thr).
// Thread = gate; Whh row lives in 16 float4 VGPRs; h broadcast from LDS.
// Writes h_t to ws, final h/c straight into d_out tail.
// -------------------------------------------------------------------------
__global__ __launch_bounds__(256) void lstm_kernel(
    const float* __restrict__ xg,     // (B,T,256), bias already included
    const float* __restrict__ Whh,    // (256,64)
    float* __restrict__ hout,         // (B,T,64)
    float* __restrict__ dout)         // full output buffer
{
    const int b   = blockIdx.x;
    const int tid = threadIdx.x;

    __shared__ __align__(16) float hs[64];
    __shared__ float gs[256];

    float4 wr[16];
    const float4* wrow = (const float4*)(Whh + (size_t)tid * 64);
    #pragma unroll
    for (int q = 0; q < 16; ++q) wr[q] = wrow[q];

    float c = 0.0f;
    if (tid < 64) hs[tid] = 0.0f;
    __syncthreads();

    const float* xgrow = xg + (size_t)b * T_ * 256;
    float* hrow = hout + (size_t)b * T_ * 64;

    for (int t = 0; t < T_; ++t) {
        float acc = xgrow[t * 256 + tid];
        const float4* h4 = (const float4*)hs;
        #pragma unroll
        for (int q = 0; q < 16; ++q) {
            float4 hv = h4[q];                   // wave-uniform broadcast read
            acc += wr[q].x * hv.x + wr[q].y * hv.y + wr[q].z * hv.z + wr[q].w * hv.w;
        }
        gs[tid] = acc;
        __syncthreads();                         // all h reads done, gates visible
        if (tid < 64) {
            const float ig = sigmoidf_(gs[tid]);
            const float fg = sigmoidf_(gs[64 + tid]);
            const float gg = tanhf_(gs[128 + tid]);
            const float og = sigmoidf_(gs[192 + tid]);
            c = fg * c + ig * gg;
            const float h = og * tanhf_(c);
            hs[tid] = h;
            hrow[t * 64 + tid] = h;
        }
        __syncthreads();                         // new h visible to all
    }
    if (tid < 64) {
        dout[B_ * T_ * 4 + b * 64 + tid]            = hs[tid];  // hT at offset 65536
        dout[B_ * T_ * 4 + B_ * 64 + b * 64 + tid]  = c;        // cT at offset 69632
    }
}

// -------------------------------------------------------------------------
// Kernel 3: head. out[bt,m] = sigmoid(h[bt,:] . hw[m,:] + hb[m]).
// 256 blocks x 256 threads; 64 rows per block staged in LDS (rows padded +4
// floats -> only 2-way bank aliasing, which is free).
// -------------------------------------------------------------------------
__global__ __launch_bounds__(256) void head_kernel(
    const float* __restrict__ hout, const float* __restrict__ hw,
    const float* __restrict__ hb, float* __restrict__ out)
{
    const int blk = blockIdx.x;
    const int tid = threadIdx.x;

    __shared__ __align__(16) float hsh[64 * 68];   // padded rows (17 float4)
    __shared__ __align__(16) float wsh[256];
    __shared__ float bsh[4];

    const float4* s4 = (const float4*)(hout + (size_t)blk * 64 * 64);
    float4* d4 = (float4*)hsh;
    for (int q = tid; q < 1024; q += 256) {
        int row = q >> 4, col = q & 15;
        d4[row * 17 + col] = s4[q];                // coalesced global read
    }
    if (tid < 64) ((float4*)wsh)[tid] = ((const float4*)hw)[tid];
    if (tid < 4)  bsh[tid] = hb[tid];
    __syncthreads();

    const int r = tid >> 2, m = tid & 3;
    const float4* hv = (const float4*)(hsh + r * 68);
    const float4* wv = (const float4*)(wsh + m * 64);
    float acc = bsh[m];
    #pragma unroll
    for (int q = 0; q < 16; ++q) {
        float4 a = hv[q], w = wv[q];
        acc += a.x * w.x + a.y * w.y + a.z * w.z + a.w * w.w;
    }
    out[(size_t)blk * 256 + tid] = sigmoidf_(acc); // coalesced
}

extern "C" void kernel_launch(void* const* d_in, const int* in_sizes, int n_in,
                              void* d_out, int out_size, void* d_ws, size_t ws_size,
                              hipStream_t stream) {
    const float* pressure = (const float*)d_in[0];
    const float* torque   = (const float*)d_in[1];
    const float* frag     = (const float*)d_in[2];
    const float* pw1 = (const float*)d_in[3];
    const float* pb1 = (const float*)d_in[4];
    const float* pw2 = (const float*)d_in[5];
    const float* pb2 = (const float*)d_in[6];
    const float* tw1 = (const float*)d_in[7];
    const float* tb1 = (const float*)d_in[8];
    const float* tw2 = (const float*)d_in[9];
    const float* tb2 = (const float*)d_in[10];
    const float* fw  = (const float*)d_in[11];
    const float* fb  = (const float*)d_in[12];
    const float* prw = (const float*)d_in[13];
    const float* prb = (const float*)d_in[14];
    const float* Wih = (const float*)d_in[15];
    const float* Whh = (const float*)d_in[16];
    const float* bih = (const float*)d_in[17];
    const float* bhh = (const float*)d_in[18];
    const float* hw  = (const float*)d_in[19];
    const float* hb  = (const float*)d_in[20];

    float* out = (float*)d_out;

    // workspace: xg (B*T*256 f32 = 16 MB) | hout (B*T*64 f32 = 4 MB)
    float* xg   = (float*)d_ws;
    float* hout = xg + (size_t)B_ * T_ * 256;

    encoder_kernel<<<B_ * T_, 64, 0, stream>>>(
        pressure, torque, frag,
        pw1, pb1, pw2, pb2, tw1, tb1, tw2, tb2,
        fw, fb, prw, prb, Wih, bih, bhh, xg);

    lstm_kernel<<<B_, 256, 0, stream>>>(xg, Whh, hout, out);

    head_kernel<<<B_ * T_ / 64, 256, 0, stream>>>(hout, hw, hb, out);
}